// Round 10
// baseline (223.693 us; speedup 1.0000x reference)
//
#include <hip/hip_runtime.h>
#include <hip/hip_bf16.h>
#include <hip/hip_fp16.h>
#include <stdint.h>

typedef unsigned short u16;
typedef __attribute__((ext_vector_type(8))) short bf16x8;
typedef __attribute__((ext_vector_type(4))) float f32x4;
typedef __attribute__((ext_vector_type(4))) _Float16 f16x4;

typedef const __attribute__((address_space(1))) unsigned int* gu32p;
typedef __attribute__((address_space(3))) unsigned int* lu32p;

__device__ __forceinline__ void gl_lds16(const u16* g, u16* l) {
  // async global->LDS DMA, 16B/lane, LDS dest = wave-uniform base + lane*16
  __builtin_amdgcn_global_load_lds((gu32p)(const void*)g, (lu32p)(void*)l, 16, 0, 0);
}

__device__ __forceinline__ u16 f2bf(float f) {
  union { float f; unsigned u; } v; v.f = f;
  unsigned r = v.u + 0x7fffu + ((v.u >> 16) & 1u);
  return (u16)(r >> 16);
}
__device__ __forceinline__ f16x4 pack4h(float a, float b, float c, float d) {
  union { f16x4 v; __half2 h[2]; } u;
  u.h[0] = __floats2half2_rn(a, b);
  u.h[1] = __floats2half2_rn(c, d);
  return u.v;
}

// ---------------- fp32 -> bf16 convert (x + 4 weights) and RoPE cos/sin table
__global__ void convert_kernel(const float4* __restrict__ x, const float4* __restrict__ wq,
                               const float4* __restrict__ wk, const float4* __restrict__ wv,
                               const float4* __restrict__ wp,
                               u16* __restrict__ xb, u16* __restrict__ wqb, u16* __restrict__ wkb,
                               u16* __restrict__ wvb, u16* __restrict__ wpb,
                               float2* __restrict__ tab) {
  int i = blockIdx.x * 256 + threadIdx.x;
  const int NX = 1048576, NW = 262144, NCONV = NX + 4 * NW;
  if (i >= NCONV) {
    int j = i - NCONV;              // 0..65535 : t*32 + d
    int d = j & 31, t = j >> 5;
    float ang = (float)t * expf(-0.28782313662425572f * (float)d);  // ln(10000)/32
    tab[j] = make_float2(cosf(ang), sinf(ang));
    return;
  }
  const float4* src; u16* dst; int off;
  if (i < NX)            { src = x;  dst = xb;  off = i; }
  else if (i < NX + NW)  { src = wq; dst = wqb; off = i - NX; }
  else if (i < NX + 2*NW){ src = wk; dst = wkb; off = i - NX - NW; }
  else if (i < NX + 3*NW){ src = wv; dst = wvb; off = i - NX - 2*NW; }
  else                   { src = wp; dst = wpb; off = i - NX - 3*NW; }
  float4 v = src[off];
  ushort4 ov = make_ushort4(f2bf(v.x), f2bf(v.y), f2bf(v.z), f2bf(v.w));
  *(ushort4*)&dst[off * 4] = ov;
}

// ---------------- NT GEMM: C[M,N] = A[M,K] * B[N,K]^T + bias, K=N=1024, M=4096
// Double-buffered single-barrier K-loop. FUSE_ROPE: rotary in epilogue for z<2.
// TRANS_V: z==2 stores output transposed as FP16 Vt[(b*1024 + c)*2048 + t].
template<int FUSE_ROPE, int OUT_BF16, int TRANS_V>
__global__ __launch_bounds__(256) void gemm_bt_kernel(
    const u16* __restrict__ A,
    const u16* __restrict__ B0, const u16* __restrict__ B1, const u16* __restrict__ B2,
    const float* __restrict__ bias0, const float* __restrict__ bias1, const float* __restrict__ bias2,
    void* out0, void* out1, void* out2, const float2* __restrict__ tab)
{
  __shared__ __align__(16) u16 As[2][4096];   // 128 x 32 per buf (64B rows)
  __shared__ __align__(16) u16 Bs[2][4096];
  const int z = blockIdx.z;
  const u16* Bw = (z == 0) ? B0 : (z == 1) ? B1 : B2;
  const float* bias = (z == 0) ? bias0 : (z == 1) ? bias1 : bias2;
  void* outv = (z == 0) ? out0 : (z == 1) ? out1 : out2;
  const int tid = threadIdx.x, lane = tid & 63, w = tid >> 6;
  const int wr = w >> 1, wc = w & 1;
  const int quad = lane >> 4, l15 = lane & 15;
  const int m0 = blockIdx.y * 128, n0 = blockIdx.x * 128;
  const int sr = lane >> 2, sc = (lane & 3) * 8;

  auto stg = [&](int kt, int bf) {
    const int k0 = kt * 32;
    #pragma unroll
    for (int p = 0; p < 2; p++) {
      gl_lds16(A  + (m0 + p*64 + w*16 + sr) * 1024 + k0 + sc, &As[bf][p*2048 + w*512]);
      gl_lds16(Bw + (n0 + p*64 + w*16 + sr) * 1024 + k0 + sc, &Bs[bf][p*2048 + w*512]);
    }
  };

  f32x4 acc[4][4] = {};
  stg(0, 0);
  for (int kt = 0; kt < 32; kt++) {
    __syncthreads();                 // tile kt landed; other buf free
    if (kt < 31) stg(kt + 1, (kt + 1) & 1);
    const int bf = kt & 1;
    bf16x8 af[4], bfr[4];
    #pragma unroll
    for (int mt = 0; mt < 4; mt++)
      af[mt] = *(const bf16x8*)&As[bf][(wr*64 + mt*16 + l15) * 32 + quad*8];
    #pragma unroll
    for (int nt = 0; nt < 4; nt++)
      bfr[nt] = *(const bf16x8*)&Bs[bf][(wc*64 + nt*16 + l15) * 32 + quad*8];
    #pragma unroll
    for (int mt = 0; mt < 4; mt++)
      #pragma unroll
      for (int nt = 0; nt < 4; nt++)
        acc[mt][nt] = __builtin_amdgcn_mfma_f32_16x16x32_bf16(af[mt], bfr[nt], acc[mt][nt], 0, 0, 0);
  }

  if (TRANS_V && z == 2) {
    // transposed FP16 store: lane holds 4 consecutive t (quad*4+r) for col c
    const int bb = m0 >> 11, tg0 = (m0 & 2047) + wr*64 + quad*4;
    #pragma unroll
    for (int nt = 0; nt < 4; nt++) {
      const int c = n0 + wc*64 + nt*16 + l15;
      const float bv = bias[c];
      u16* vrow = (u16*)outv + (size_t)(bb*1024 + c) * 2048 + tg0;
      #pragma unroll
      for (int mt = 0; mt < 4; mt++) {
        ushort4 pk;
        pk.x = __half_as_ushort(__float2half_rn(acc[mt][nt][0] + bv));
        pk.y = __half_as_ushort(__float2half_rn(acc[mt][nt][1] + bv));
        pk.z = __half_as_ushort(__float2half_rn(acc[mt][nt][2] + bv));
        pk.w = __half_as_ushort(__float2half_rn(acc[mt][nt][3] + bv));
        *(ushort4*)&vrow[mt*16] = pk;
      }
    }
    return;
  }

  #pragma unroll
  for (int mt = 0; mt < 4; mt++) {
    #pragma unroll
    for (int r = 0; r < 4; r++) {
      const int row = m0 + wr*64 + mt*16 + quad*4 + r;
      float v[4];
      #pragma unroll
      for (int nt = 0; nt < 4; nt++)
        v[nt] = acc[mt][nt][r] + bias[n0 + wc*64 + nt*16 + l15];
      if (FUSE_ROPE && z < 2) {
        const int t = row & 2047;
        #pragma unroll
        for (int nt = 0; nt < 2; nt++) {
          const int d = nt*16 + l15;
          float2 cs = tab[t*32 + d];
          float x0 = v[nt], x1 = v[nt+2];
          v[nt]   = x0 * cs.x - x1 * cs.y;
          v[nt+2] = x1 * cs.x + x0 * cs.y;
        }
      }
      #pragma unroll
      for (int nt = 0; nt < 4; nt++) {
        const int col = n0 + wc*64 + nt*16 + l15;
        if (OUT_BF16) ((u16*)outv)[row * 1024 + col] = f2bf(v[nt]);
        else          ((float*)outv)[row * 1024 + col] = v[nt];
      }
    }
  }
}

// ---------------- causal flash attention, S^T formulation (NO P LDS round-trip).
// Block x: tiles A (qt=x), B (qt=15-x); 8 waves, each owns 16 rows of BOTH tiles.
// QK^T computed TRANSPOSED: S^T = mfma(A=K-frag, B=Q-frag) -> C-layout
// col=qrow=l15, row=key=quad*4+r. That C-layout IS the B-operand layout of
// mfma_f32_16x16x16f16 (n=l15, k=quad*4+j), so P goes exp2 -> pack f16 ->
// PV MFMA entirely in-register. O^T[d][q] += mfma(A=Vt-frag(f16 b64), B=P-frag).
// Row-sum l via ones-A-frag MFMA (in-lane). K/V staged async double-buffered,
// XOR-swizzled (R8's verified staging).
__global__ __launch_bounds__(512) void attn_kernel(
    const u16* __restrict__ qg, const u16* __restrict__ kg,
    const u16* __restrict__ vtg, u16* __restrict__ yg)
{
  __shared__ __align__(16) u16 K_lds[2][128 * 64];   // bf16 [s][d], chunk swz ^(s&7)
  __shared__ __align__(16) u16 V_lds[2][64 * 128];   // fp16 [d][s], chunk swz ^(d&15)
  const int x = blockIdx.x;                // 0..7
  const int hh = blockIdx.y, b = blockIdx.z;
  const int tid = threadIdx.x, lane = tid & 63, w = tid >> 6;   // w: 0..7
  const int quad = lane >> 4, l15 = lane & 15;
  const int bh = b * (2048 * 1024) + hh * 64;
  const int vtb = (b * 16 + hh) * 131072;  // Vt: [b,h][64 d][2048 t], fp16

  const int qtA = x, qtB = 15 - x;
  const int qrl = w*16 + l15;              // this lane's q-row within a tile

  bf16x8 qfA[2], qfB[2];
  {
    const int rA = qtA*128 + qrl, rB = qtB*128 + qrl;
    qfA[0] = *(const bf16x8*)&qg[bh + rA*1024 + quad*8];
    qfA[1] = *(const bf16x8*)&qg[bh + rA*1024 + 32 + quad*8];
    qfB[0] = *(const bf16x8*)&qg[bh + rB*1024 + quad*8];
    qfB[1] = *(const bf16x8*)&qg[bh + rB*1024 + 32 + quad*8];
  }
  f32x4 oA[4] = {}, oB[4] = {};            // O^T: [dt], col=q=l15, row d=dt*16+quad*4+r
  f32x4 lA = {}, lB = {};                  // row-sum accumulators (all rows equal)

  f16x4 onesh;
  #pragma unroll
  for (int i2 = 0; i2 < 4; i2++) onesh[i2] = (_Float16)1.0f;

  const float c = 0.18033688011112042f;    // (1/sqrt(64)) * log2(e)

  auto do_stage = [&](int j, int bf) {
    #pragma unroll
    for (int p = 0; p < 2; p++) {          // K: 16 segs of 8 rows x 64
      const int seg = w*2 + p;
      const int r = seg*8 + (lane >> 3);
      const int g = (lane & 7) ^ (r & 7);
      gl_lds16(kg + bh + (j*128 + r) * 1024 + g*8, &K_lds[bf][seg*512]);
    }
    #pragma unroll
    for (int p = 0; p < 2; p++) {          // Vt: 16 segs of 4 rows x 128
      const int seg = w*2 + p;
      const int r = seg*4 + (lane >> 4);
      const int g = (lane & 15) ^ (r & 15);
      gl_lds16(vtg + vtb + r * 2048 + j*128 + g*8, &V_lds[bf][seg*512]);
    }
  };

  do_stage(0, 0);
  for (int j = 0; j <= qtB; j++) {
    __syncthreads();                       // stripe j landed; other buf free
    if (j < qtB) do_stage(j + 1, (j + 1) & 1);
    const int bf = j & 1;
    const bool doA = (j <= qtA);           // block-uniform

    // ---- S^T = K Q^T : K-frags read once, shared by both tiles
    // logical chunk c at row r lives at phys chunk c^(r&7); here r&7 = l15&7.
    f32x4 sA[8], sB[8];
    #pragma unroll
    for (int nt = 0; nt < 8; nt++) {
      const int krow = (nt*16 + l15) * 64;
      const int g0 = ((quad)     ^ (l15 & 7)) * 8;   // logical chunk quad   (d 0..31)
      const int g1 = ((4 + quad) ^ (l15 & 7)) * 8;   // logical chunk 4+quad (d 32..63)
      bf16x8 kf0 = *(const bf16x8*)&K_lds[bf][krow + g0];
      bf16x8 kf1 = *(const bf16x8*)&K_lds[bf][krow + g1];
      f32x4 z = {};
      z = __builtin_amdgcn_mfma_f32_16x16x32_bf16(kf0, qfB[0], z, 0, 0, 0);
      z = __builtin_amdgcn_mfma_f32_16x16x32_bf16(kf1, qfB[1], z, 0, 0, 0);
      sB[nt] = z;
      if (doA) {
        f32x4 za = {};
        za = __builtin_amdgcn_mfma_f32_16x16x32_bf16(kf0, qfA[0], za, 0, 0, 0);
        za = __builtin_amdgcn_mfma_f32_16x16x32_bf16(kf1, qfA[1], za, 0, 0, 0);
        sA[nt] = za;
      }
    }
    // ---- p = exp2(s*c) -> f16 B-frags in-register (no LDS)
    f16x4 pfA[8], pfB[8];
    const bool dgB = (j == qtB), dgA = (j == qtA);
    #pragma unroll
    for (int nt = 0; nt < 8; nt++) {
      float pb[4];
      #pragma unroll
      for (int r = 0; r < 4; r++) {
        float sv = sB[nt][r] * c;
        if (dgB && (nt*16 + quad*4 + r > qrl)) sv = -1e30f;
        pb[r] = exp2f(sv);
      }
      pfB[nt] = pack4h(pb[0], pb[1], pb[2], pb[3]);
      lB = __builtin_amdgcn_mfma_f32_16x16x16f16(onesh, pfB[nt], lB, 0, 0, 0);
    }
    if (doA) {
      #pragma unroll
      for (int nt = 0; nt < 8; nt++) {
        float pa[4];
        #pragma unroll
        for (int r = 0; r < 4; r++) {
          float sv = sA[nt][r] * c;
          if (dgA && (nt*16 + quad*4 + r > qrl)) sv = -1e30f;
          pa[r] = exp2f(sv);
        }
        pfA[nt] = pack4h(pa[0], pa[1], pa[2], pa[3]);
        lA = __builtin_amdgcn_mfma_f32_16x16x16f16(onesh, pfA[nt], lA, 0, 0, 0);
      }
    }
    // ---- O^T += Vt P : V-frags b64 (f16), read once, shared by both tiles
    #pragma unroll
    for (int nt = 0; nt < 8; nt++) {
      const int pp = ((nt*2 + (quad >> 1)) ^ l15) * 8 + (quad & 1) * 4;
      #pragma unroll
      for (int dt = 0; dt < 4; dt++) {
        f16x4 vf = *(const f16x4*)&V_lds[bf][(dt*16 + l15) * 128 + pp];
        oB[dt] = __builtin_amdgcn_mfma_f32_16x16x16f16(vf, pfB[nt], oB[dt], 0, 0, 0);
        if (doA) oA[dt] = __builtin_amdgcn_mfma_f32_16x16x16f16(vf, pfA[nt], oA[dt], 0, 0, 0);
      }
    }
  }

  // ---- epilogue: normalize, store bf16 (lane = fixed q-row, 4 d per ushort4)
  const float iA = 1.0f / lA[0], iB = 1.0f / lB[0];
  #pragma unroll
  for (int dt = 0; dt < 4; dt++) {
    ushort4 pk;
    u16* yA = &yg[bh + (qtA*128 + qrl) * 1024 + dt*16 + quad*4];
    pk.x = f2bf(oA[dt][0] * iA); pk.y = f2bf(oA[dt][1] * iA);
    pk.z = f2bf(oA[dt][2] * iA); pk.w = f2bf(oA[dt][3] * iA);
    *(ushort4*)yA = pk;
    u16* yB = &yg[bh + (qtB*128 + qrl) * 1024 + dt*16 + quad*4];
    pk.x = f2bf(oB[dt][0] * iB); pk.y = f2bf(oB[dt][1] * iB);
    pk.z = f2bf(oB[dt][2] * iB); pk.w = f2bf(oB[dt][3] * iB);
    *(ushort4*)yB = pk;
  }
}

extern "C" void kernel_launch(void* const* d_in, const int* in_sizes, int n_in,
                              void* d_out, int out_size, void* d_ws, size_t ws_size,
                              hipStream_t stream) {
  const float* x  = (const float*)d_in[0];
  const float* Wq = (const float*)d_in[1];
  const float* bq = (const float*)d_in[2];
  const float* Wk = (const float*)d_in[3];
  const float* bk = (const float*)d_in[4];
  const float* Wv = (const float*)d_in[5];
  const float* bv = (const float*)d_in[6];
  const float* Wp = (const float*)d_in[7];
  const float* bp = (const float*)d_in[8];

  char* ws = (char*)d_ws;
  u16* xb  = (u16*)(ws);                   // 8 MB, reused as attention output y
  u16* wqb = (u16*)(ws + (8u  << 20));
  u16* wkb = (u16*)(ws + (10u << 20));
  u16* wvb = (u16*)(ws + (12u << 20));
  u16* wpb = (u16*)(ws + (14u << 20));
  u16* qb  = (u16*)(ws + (16u << 20));
  u16* kb  = (u16*)(ws + (24u << 20));
  u16* vtb = (u16*)(ws + (32u << 20));     // V transposed FP16: [b,h,d][t], 8 MB
  float2* tab = (float2*)(ws + (40u << 20));
  u16* yb = xb;

  convert_kernel<<<8448, 256, 0, stream>>>((const float4*)x, (const float4*)Wq, (const float4*)Wk,
                                           (const float4*)Wv, (const float4*)Wp,
                                           xb, wqb, wkb, wvb, wpb, tab);
  gemm_bt_kernel<1, 1, 1><<<dim3(8, 32, 3), 256, 0, stream>>>(xb, wqb, wkb, wvb, bq, bk, bv,
                                                              (void*)qb, (void*)kb, (void*)vtb, tab);
  attn_kernel<<<dim3(8, 16, 2), 512, 0, stream>>>(qb, kb, vtb, yb);
  gemm_bt_kernel<0, 0, 0><<<dim3(8, 32, 1), 256, 0, stream>>>(yb, wpb, wpb, wpb, bp, bp, bp,
                                                              (void*)d_out, (void*)d_out, (void*)d_out, tab);
}